// Round 1
// baseline (7111.342 us; speedup 1.0000x reference)
//
#include <hip/hip_runtime.h>
#include <math.h>

#define BN 4
#define CHN 64
#define HH 256
#define WW 256
#define HWSZ (HH*WW)
#define EPSV 1e-5f

__device__ __forceinline__ int refl(int i, int n) {
    if (i < 0) i = -i;
    if (i >= n) i = 2*n - 2 - i;
    return i;
}

// K[b,t,y,x] = exp(-0.5*(g(refl(y+dy),refl(x+dx)) - g(y,x))^2)
__global__ void guide_kernel(const float* __restrict__ x, float* __restrict__ Kb) {
    int idx = blockIdx.x * 256 + threadIdx.x;
    if (idx >= BN*HWSZ) return;
    int b = idx / HWSZ, p = idx - b*HWSZ;
    int y = p / WW, xx = p - y*WW;
    const float* g = x + b*HWSZ;
    float gc = g[p];
#pragma unroll
    for (int t = 0; t < 9; ++t) {
        int yy  = refl(y + t/3 - 1, HH);
        int xx2 = refl(xx + t%3 - 1, WW);
        float d = g[yy*WW + xx2] - gc;
        Kb[(b*9 + t)*HWSZ + p] = __expf(-0.5f*d*d);
    }
}

// w[o][c][t] -> wt[c][o][t]  (contiguous per-c for scalar-cache locality)
__global__ void transpose_w(const float* __restrict__ w, float* __restrict__ wt) {
    int idx = blockIdx.x*256 + threadIdx.x;
    if (idx >= CHN*CHN*9) return;
    int t = idx % 9;
    int c = (idx/9) % CHN;
    int o = idx/(9*CHN);
    wt[(c*CHN + o)*9 + t] = w[idx];
}

__global__ void conv1x1_kernel(const float* __restrict__ x, const float* __restrict__ w0,
                               const float* __restrict__ b0, float* __restrict__ out) {
    int idx = blockIdx.x*256 + threadIdx.x;           // over BN*CHN*HWSZ/4
    const int q = HWSZ/4;
    int p = idx % q;
    int o = (idx/q) % CHN;
    int b = idx/(q*CHN);
    const float4* x4 = (const float4*)(x + (size_t)b*HWSZ);
    float4 v = x4[p];
    float wv = w0[o], bv = b0[o];
    float4 r;
    r.x = fmaf(wv, v.x, bv); r.y = fmaf(wv, v.y, bv);
    r.z = fmaf(wv, v.z, bv); r.w = fmaf(wv, v.w, bv);
    ((float4*)out)[idx] = r;
}

// Direct PAC conv: 1 thread = 1 pixel, 64 output-channel accumulators.
// Weights read through wave-uniform addresses -> SGPRs (s_load), so the
// inner loop is pure v_fmac with one vector operand.
template<bool HASK, bool FRELU>
__global__ void __launch_bounds__(256) pac_kernel(
    const float* __restrict__ h, const float* __restrict__ Kb,
    const float* __restrict__ wt, const float* __restrict__ bias,
    float* __restrict__ out)
{
    int b = blockIdx.z;
    int y = blockIdx.y*16 + (threadIdx.x >> 4);
    int x = blockIdx.x*16 + (threadIdx.x & 15);
    int p = y*WW + x;

    int off[9];
    float m[9];
#pragma unroll
    for (int t = 0; t < 9; ++t) {
        off[t] = refl(y + t/3 - 1, HH)*WW + refl(x + t%3 - 1, WW);
        m[t] = HASK ? Kb[(b*9 + t)*HWSZ + p] : 1.0f;
    }

    const float* hb = h + (size_t)b*CHN*HWSZ;
    float acc[CHN];
#pragma unroll
    for (int o = 0; o < CHN; ++o) acc[o] = 0.f;

    // prefetch c=0 taps (already modulated)
    float v[9];
#pragma unroll
    for (int t = 0; t < 9; ++t) v[t] = hb[off[t]] * m[t];

    for (int c = 0; c < CHN; ++c) {
        float vn[9];
        if (c + 1 < CHN) {
            const float* hn = hb + (c+1)*HWSZ;
#pragma unroll
            for (int t = 0; t < 9; ++t) vn[t] = hn[off[t]] * m[t];
        }
        const float* wc = wt + c*CHN*9;
#pragma unroll
        for (int o = 0; o < CHN; ++o) {
            const float* wo = wc + o*9;
#pragma unroll
            for (int t = 0; t < 9; ++t) acc[o] = fmaf(wo[t], v[t], acc[o]);
        }
#pragma unroll
        for (int t = 0; t < 9; ++t) v[t] = vn[t];
    }

    float* ob = out + (size_t)b*CHN*HWSZ + p;
#pragma unroll
    for (int o = 0; o < CHN; ++o) {
        float r = acc[o] + bias[o];
        if (FRELU) r = fmaxf(r, 0.f);
        ob[o*HWSZ] = r;
    }
}

// per-(b,c) mean / rstd over HWSZ
__global__ void __launch_bounds__(256) stats_kernel(const float* __restrict__ xin,
                                                    float* __restrict__ stats) {
    int bc = blockIdx.x;
    const float4* p4 = (const float4*)(xin + (size_t)bc*HWSZ);
    float s1 = 0.f, s2 = 0.f;
    for (int i = threadIdx.x; i < HWSZ/4; i += 256) {
        float4 v = p4[i];
        s1 += v.x + v.y + v.z + v.w;
        s2 += v.x*v.x + v.y*v.y + v.z*v.z + v.w*v.w;
    }
#pragma unroll
    for (int d = 32; d; d >>= 1) { s1 += __shfl_down(s1, d); s2 += __shfl_down(s2, d); }
    __shared__ float ls[8];
    int wid = threadIdx.x >> 6;
    if ((threadIdx.x & 63) == 0) { ls[wid] = s1; ls[wid+4] = s2; }
    __syncthreads();
    if (threadIdx.x == 0) {
        float t1 = ls[0]+ls[1]+ls[2]+ls[3];
        float t2 = ls[4]+ls[5]+ls[6]+ls[7];
        float mean = t1 * (1.f/HWSZ);
        float var  = t2 * (1.f/HWSZ) - mean*mean;
        stats[bc*2]   = mean;
        stats[bc*2+1] = rsqrtf(fmaxf(var, 0.f) + EPSV);
    }
}

__global__ void applyrelu_kernel(float* __restrict__ xio, const float* __restrict__ stats) {
    int idx = blockIdx.x*256 + threadIdx.x;           // BN*CHN*HWSZ/4
    int bc = idx / (HWSZ/4);
    float mean = stats[bc*2], r = stats[bc*2+1];
    float4 v = ((float4*)xio)[idx];
    v.x = fmaxf((v.x-mean)*r, 0.f);
    v.y = fmaxf((v.y-mean)*r, 0.f);
    v.z = fmaxf((v.z-mean)*r, 0.f);
    v.w = fmaxf((v.w-mean)*r, 0.f);
    ((float4*)xio)[idx] = v;
}

// a = relu(a + (c - mean)*rstd)   (residual add + norm + relu, in place on a)
__global__ void addnorm_relu_kernel(float* __restrict__ a, const float* __restrict__ cc,
                                    const float* __restrict__ stats) {
    int idx = blockIdx.x*256 + threadIdx.x;           // BN*CHN*HWSZ/4
    int bc = idx / (HWSZ/4);
    float mean = stats[bc*2], r = stats[bc*2+1];
    float4 t = ((float4*)a)[idx];
    float4 v = ((const float4*)cc)[idx];
    t.x = fmaxf(t.x + (v.x-mean)*r, 0.f);
    t.y = fmaxf(t.y + (v.y-mean)*r, 0.f);
    t.z = fmaxf(t.z + (v.z-mean)*r, 0.f);
    t.w = fmaxf(t.w + (v.w-mean)*r, 0.f);
    ((float4*)a)[idx] = t;
}

extern "C" void kernel_launch(void* const* d_in, const int* in_sizes, int n_in,
                              void* d_out, int out_size, void* d_ws, size_t ws_size,
                              hipStream_t stream) {
    const float* x   = (const float*)d_in[0];
    // d_in[1] = grad_img: unused by the reference
    const float* w0  = (const float*)d_in[2];
    const float* b0  = (const float*)d_in[3];
    const float* wf  = (const float*)d_in[4];
    const float* bf  = (const float*)d_in[5];
    const float* w1a = (const float*)d_in[6];  const float* b1a = (const float*)d_in[7];
    const float* w1b = (const float*)d_in[8];  const float* b1b = (const float*)d_in[9];
    const float* w2a = (const float*)d_in[10]; const float* b2a = (const float*)d_in[11];
    const float* w2b = (const float*)d_in[12]; const float* b2b = (const float*)d_in[13];
    const float* w3a = (const float*)d_in[14]; const float* b3a = (const float*)d_in[15];
    const float* w3b = (const float*)d_in[16]; const float* b3b = (const float*)d_in[17];

    float* ws    = (float*)d_ws;
    float* Kb    = ws;                               // BN*9*HWSZ      = 2,359,296
    float* A     = Kb + (size_t)BN*9*HWSZ;           // BN*CHN*HWSZ    = 4,194,304
    float* Bb    = A  + (size_t)BN*CHN*HWSZ;         // BN*CHN*HWSZ
    float* stats = Bb + (size_t)BN*CHN*HWSZ;         // BN*CHN*2
    float* wt    = stats + BN*CHN*2;                 // 7 * CHN*CHN*9  = 258,048
    float* Cc    = (float*)d_out;                    // scratch + final output

    const float* wsrc[7] = {w1a, w1b, w2a, w2b, w3a, w3b, wf};
    for (int i = 0; i < 7; ++i)
        transpose_w<<<(CHN*CHN*9 + 255)/256, 256, 0, stream>>>(wsrc[i], wt + (size_t)i*CHN*CHN*9);

    guide_kernel<<<(BN*HWSZ + 255)/256, 256, 0, stream>>>(x, Kb);
    conv1x1_kernel<<<BN*CHN*HWSZ/4/256, 256, 0, stream>>>(x, w0, b0, A);

    dim3 g(WW/16, HH/16, BN);
    const int eblk = BN*CHN*HWSZ/4/256;
    const float* biasA[3] = {b1a, b2a, b3a};
    const float* biasB[3] = {b1b, b2b, b3b};

    for (int rb = 0; rb < 3; ++rb) {
        pac_kernel<true,false><<<g, 256, 0, stream>>>(A, Kb, wt + (size_t)(2*rb)*CHN*CHN*9, biasA[rb], Bb);
        stats_kernel<<<BN*CHN, 256, 0, stream>>>(Bb, stats);
        applyrelu_kernel<<<eblk, 256, 0, stream>>>(Bb, stats);
        pac_kernel<true,false><<<g, 256, 0, stream>>>(Bb, Kb, wt + (size_t)(2*rb+1)*CHN*CHN*9, biasB[rb], Cc);
        stats_kernel<<<BN*CHN, 256, 0, stream>>>(Cc, stats);
        addnorm_relu_kernel<<<eblk, 256, 0, stream>>>(A, Cc, stats);
    }

    // final: plain 3x3 conv (K==1) + bias + relu
    pac_kernel<false,true><<<g, 256, 0, stream>>>(A, Kb, wt + (size_t)6*CHN*CHN*9, bf, Cc);
}

// Round 2
// 2690.172 us; speedup vs baseline: 2.6435x; 2.6435x over previous
//
#include <hip/hip_runtime.h>
#include <math.h>

#define BN 4
#define CHN 64
#define OTILE 32
#define HH 256
#define WW 256
#define HWSZ (HH*WW)
#define EPSV 1e-5f

__device__ __forceinline__ int refl(int i, int n) {
    if (i < 0) i = -i;
    if (i >= n) i = 2*n - 2 - i;
    return i;
}

// K[b,t,y,x] = exp(-0.5*(g(refl(y+dy),refl(x+dx)) - g(y,x))^2)
__global__ void guide_kernel(const float* __restrict__ x, float* __restrict__ Kb) {
    int idx = blockIdx.x * 256 + threadIdx.x;
    if (idx >= BN*HWSZ) return;
    int b = idx / HWSZ, p = idx - b*HWSZ;
    int y = p / WW, xx = p - y*WW;
    const float* g = x + b*HWSZ;
    float gc = g[p];
#pragma unroll
    for (int t = 0; t < 9; ++t) {
        int yy  = refl(y + t/3 - 1, HH);
        int xx2 = refl(xx + t%3 - 1, WW);
        float d = g[yy*WW + xx2] - gc;
        Kb[(b*9 + t)*HWSZ + p] = __expf(-0.5f*d*d);
    }
}

// w[o][c][t] -> wt[c][o][t]  (contiguous per-c; wave-uniform addresses in pac)
__global__ void transpose_w(const float* __restrict__ w, float* __restrict__ wt) {
    int idx = blockIdx.x*256 + threadIdx.x;
    if (idx >= CHN*CHN*9) return;
    int t = idx % 9;
    int c = (idx/9) % CHN;
    int o = idx/(9*CHN);
    wt[(c*CHN + o)*9 + t] = w[idx];
}

__global__ void conv1x1_kernel(const float* __restrict__ x, const float* __restrict__ w0,
                               const float* __restrict__ b0, float* __restrict__ out) {
    int idx = blockIdx.x*256 + threadIdx.x;           // over BN*CHN*HWSZ/4
    const int q = HWSZ/4;
    int p = idx % q;
    int o = (idx/q) % CHN;
    int b = idx/(q*CHN);
    const float4* x4 = (const float4*)(x + (size_t)b*HWSZ);
    float4 v = x4[p];
    float wv = w0[o], bv = b0[o];
    float4 r;
    r.x = fmaf(wv, v.x, bv); r.y = fmaf(wv, v.y, bv);
    r.z = fmaf(wv, v.z, bv); r.w = fmaf(wv, v.w, bv);
    ((float4*)out)[idx] = r;
}

// Direct PAC conv: 1 thread = 1 pixel, OTILE=32 output-channel accumulators
// (two o-passes via gridDim.z). launch_bounds(256,2) -> 256-VGPR budget,
// no scratch spill (round-1 failure mode: default bounds spilled acc[64]).
// Weights are wave-uniform -> s_load into SGPRs; inner loop is pure v_fmac.
template<bool HASK, bool FRELU>
__global__ void __launch_bounds__(256, 2) pac_kernel(
    const float* __restrict__ h, const float* __restrict__ Kb,
    const float* __restrict__ wt, const float* __restrict__ bias,
    float* __restrict__ out)
{
    int bz = blockIdx.z;
    int b  = bz >> 1;
    int o0 = (bz & 1) * OTILE;
    int y = blockIdx.y*16 + (threadIdx.x >> 4);
    int x = blockIdx.x*16 + (threadIdx.x & 15);
    int p = y*WW + x;

    int off[9];
    float m[9];
#pragma unroll
    for (int t = 0; t < 9; ++t) {
        off[t] = refl(y + t/3 - 1, HH)*WW + refl(x + t%3 - 1, WW);
        m[t] = HASK ? Kb[(b*9 + t)*HWSZ + p] : 1.0f;
    }

    const float* hb = h + (size_t)b*CHN*HWSZ;
    float acc[OTILE];
#pragma unroll
    for (int o = 0; o < OTILE; ++o) acc[o] = 0.f;

    // prefetch c=0 taps (already modulated)
    float v[9];
#pragma unroll
    for (int t = 0; t < 9; ++t) v[t] = hb[off[t]] * m[t];

    for (int c = 0; c < CHN; ++c) {
        float vn[9];
#pragma unroll
        for (int t = 0; t < 9; ++t) vn[t] = 0.f;
        if (c + 1 < CHN) {
            const float* hn = hb + (c+1)*HWSZ;
#pragma unroll
            for (int t = 0; t < 9; ++t) vn[t] = hn[off[t]] * m[t];
        }
        const float* wc = wt + ((size_t)c*CHN + o0)*9;
#pragma unroll
        for (int o = 0; o < OTILE; ++o) {
#pragma unroll
            for (int t = 0; t < 9; ++t) acc[o] = fmaf(wc[o*9 + t], v[t], acc[o]);
        }
#pragma unroll
        for (int t = 0; t < 9; ++t) v[t] = vn[t];
    }

    float* ob = out + (size_t)b*CHN*HWSZ + (size_t)o0*HWSZ + p;
#pragma unroll
    for (int o = 0; o < OTILE; ++o) {
        float r = acc[o] + bias[o0 + o];
        if (FRELU) r = fmaxf(r, 0.f);
        ob[o*HWSZ] = r;
    }
}

// per-(b,c) mean / rstd over HWSZ
__global__ void __launch_bounds__(256) stats_kernel(const float* __restrict__ xin,
                                                    float* __restrict__ stats) {
    int bc = blockIdx.x;
    const float4* p4 = (const float4*)(xin + (size_t)bc*HWSZ);
    float s1 = 0.f, s2 = 0.f;
    for (int i = threadIdx.x; i < HWSZ/4; i += 256) {
        float4 v = p4[i];
        s1 += v.x + v.y + v.z + v.w;
        s2 += v.x*v.x + v.y*v.y + v.z*v.z + v.w*v.w;
    }
#pragma unroll
    for (int d = 32; d; d >>= 1) { s1 += __shfl_down(s1, d); s2 += __shfl_down(s2, d); }
    __shared__ float ls[8];
    int wid = threadIdx.x >> 6;
    if ((threadIdx.x & 63) == 0) { ls[wid] = s1; ls[wid+4] = s2; }
    __syncthreads();
    if (threadIdx.x == 0) {
        float t1 = ls[0]+ls[1]+ls[2]+ls[3];
        float t2 = ls[4]+ls[5]+ls[6]+ls[7];
        float mean = t1 * (1.f/HWSZ);
        float var  = t2 * (1.f/HWSZ) - mean*mean;
        stats[bc*2]   = mean;
        stats[bc*2+1] = rsqrtf(fmaxf(var, 0.f) + EPSV);
    }
}

__global__ void applyrelu_kernel(float* __restrict__ xio, const float* __restrict__ stats) {
    int idx = blockIdx.x*256 + threadIdx.x;           // BN*CHN*HWSZ/4
    int bc = idx / (HWSZ/4);
    float mean = stats[bc*2], r = stats[bc*2+1];
    float4 v = ((float4*)xio)[idx];
    v.x = fmaxf((v.x-mean)*r, 0.f);
    v.y = fmaxf((v.y-mean)*r, 0.f);
    v.z = fmaxf((v.z-mean)*r, 0.f);
    v.w = fmaxf((v.w-mean)*r, 0.f);
    ((float4*)xio)[idx] = v;
}

// a = relu(a + (c - mean)*rstd)   (residual add + norm + relu, in place on a)
__global__ void addnorm_relu_kernel(float* __restrict__ a, const float* __restrict__ cc,
                                    const float* __restrict__ stats) {
    int idx = blockIdx.x*256 + threadIdx.x;           // BN*CHN*HWSZ/4
    int bc = idx / (HWSZ/4);
    float mean = stats[bc*2], r = stats[bc*2+1];
    float4 t = ((float4*)a)[idx];
    float4 v = ((const float4*)cc)[idx];
    t.x = fmaxf(t.x + (v.x-mean)*r, 0.f);
    t.y = fmaxf(t.y + (v.y-mean)*r, 0.f);
    t.z = fmaxf(t.z + (v.z-mean)*r, 0.f);
    t.w = fmaxf(t.w + (v.w-mean)*r, 0.f);
    ((float4*)a)[idx] = t;
}

extern "C" void kernel_launch(void* const* d_in, const int* in_sizes, int n_in,
                              void* d_out, int out_size, void* d_ws, size_t ws_size,
                              hipStream_t stream) {
    const float* x   = (const float*)d_in[0];
    // d_in[1] = grad_img: unused by the reference
    const float* w0  = (const float*)d_in[2];
    const float* b0  = (const float*)d_in[3];
    const float* wf  = (const float*)d_in[4];
    const float* bf  = (const float*)d_in[5];
    const float* w1a = (const float*)d_in[6];  const float* b1a = (const float*)d_in[7];
    const float* w1b = (const float*)d_in[8];  const float* b1b = (const float*)d_in[9];
    const float* w2a = (const float*)d_in[10]; const float* b2a = (const float*)d_in[11];
    const float* w2b = (const float*)d_in[12]; const float* b2b = (const float*)d_in[13];
    const float* w3a = (const float*)d_in[14]; const float* b3a = (const float*)d_in[15];
    const float* w3b = (const float*)d_in[16]; const float* b3b = (const float*)d_in[17];

    float* ws    = (float*)d_ws;
    float* Kb    = ws;                               // BN*9*HWSZ      = 2,359,296
    float* A     = Kb + (size_t)BN*9*HWSZ;           // BN*CHN*HWSZ    = 4,194,304
    float* Bb    = A  + (size_t)BN*CHN*HWSZ;         // BN*CHN*HWSZ
    float* stats = Bb + (size_t)BN*CHN*HWSZ;         // BN*CHN*2
    float* wt    = stats + BN*CHN*2;                 // 7 * CHN*CHN*9  = 258,048
    float* Cc    = (float*)d_out;                    // scratch + final output

    const float* wsrc[7] = {w1a, w1b, w2a, w2b, w3a, w3b, wf};
    for (int i = 0; i < 7; ++i)
        transpose_w<<<(CHN*CHN*9 + 255)/256, 256, 0, stream>>>(wsrc[i], wt + (size_t)i*CHN*CHN*9);

    guide_kernel<<<(BN*HWSZ + 255)/256, 256, 0, stream>>>(x, Kb);
    conv1x1_kernel<<<BN*CHN*HWSZ/4/256, 256, 0, stream>>>(x, w0, b0, A);

    dim3 g(WW/16, HH/16, BN*2);                      // z = batch * 2 o-passes
    const int eblk = BN*CHN*HWSZ/4/256;
    const float* biasA[3] = {b1a, b2a, b3a};
    const float* biasB[3] = {b1b, b2b, b3b};

    for (int rb = 0; rb < 3; ++rb) {
        pac_kernel<true,false><<<g, 256, 0, stream>>>(A, Kb, wt + (size_t)(2*rb)*CHN*CHN*9, biasA[rb], Bb);
        stats_kernel<<<BN*CHN, 256, 0, stream>>>(Bb, stats);
        applyrelu_kernel<<<eblk, 256, 0, stream>>>(Bb, stats);
        pac_kernel<true,false><<<g, 256, 0, stream>>>(Bb, Kb, wt + (size_t)(2*rb+1)*CHN*CHN*9, biasB[rb], Cc);
        stats_kernel<<<BN*CHN, 256, 0, stream>>>(Cc, stats);
        addnorm_relu_kernel<<<eblk, 256, 0, stream>>>(A, Cc, stats);
    }

    // final: plain 3x3 conv (K==1) + bias + relu
    pac_kernel<false,true><<<g, 256, 0, stream>>>(A, Kb, wt + (size_t)6*CHN*CHN*9, bf, Cc);
}

// Round 3
// 1013.458 us; speedup vs baseline: 7.0169x; 2.6544x over previous
//
#include <hip/hip_runtime.h>
#include <hip/hip_bf16.h>
#include <math.h>

#define BN 4
#define CHN 64
#define HH 256
#define WW 256
#define HWSZ (HH*WW)
#define EPSV 1e-5f
#define NT 64   // pixel tile per block

typedef __attribute__((ext_vector_type(8))) short short8;
typedef __attribute__((ext_vector_type(4))) float floatx4;

__device__ __forceinline__ int refl(int i, int n) {
    if (i < 0) i = -i;
    if (i >= n) i = 2*n - 2 - i;
    return i;
}

__device__ __forceinline__ short f2bf(float f) {
    __hip_bfloat16 h = __float2bfloat16(f);   // RNE
    return __builtin_bit_cast(short, h);
}

// K[b,t,y,x] = exp(-0.5*(g(refl(y+dy),refl(x+dx)) - g(y,x))^2)  (fp32)
__global__ void guide_kernel(const float* __restrict__ x, float* __restrict__ Kb) {
    int idx = blockIdx.x * 256 + threadIdx.x;
    if (idx >= BN*HWSZ) return;
    int b = idx / HWSZ, p = idx - b*HWSZ;
    int y = p / WW, xx = p - y*WW;
    const float* g = x + b*HWSZ;
    float gc = g[p];
#pragma unroll
    for (int t = 0; t < 9; ++t) {
        int yy  = refl(y + t/3 - 1, HH);
        int xx2 = refl(xx + t%3 - 1, WW);
        float d = g[yy*WW + xx2] - gc;
        Kb[(b*9 + t)*HWSZ + p] = __expf(-0.5f*d*d);
    }
}

// Pack w[o][c][t] (fp32, OIHW with HW flattened as t) into bf16 A-fragments:
// Ap[((t*2+kh)*4 + wave)*64 + lane][j]  with  o = wave*16 + (lane&15),
// c = kh*32 + (lane>>4)*8 + j   (A[m=lane&15][k=quad*8+j], m120-verified).
__global__ void pack_w(const float* __restrict__ w, short* __restrict__ Ap) {
    int tid = blockIdx.x*256 + threadIdx.x;
    if (tid >= 9*2*4*64*8) return;
    int j    = tid & 7;
    int lane = (tid >> 3) & 63;
    int wave = (tid >> 9) & 3;
    int kh   = (tid >> 11) & 1;
    int t    = tid >> 12;
    int o = wave*16 + (lane & 15);
    int c = kh*32 + (lane >> 4)*8 + j;
    Ap[tid] = f2bf(w[(o*CHN + c)*9 + t]);
}

__global__ void conv1x1_kernel(const float* __restrict__ x, const float* __restrict__ w0,
                               const float* __restrict__ b0, float* __restrict__ out) {
    int idx = blockIdx.x*256 + threadIdx.x;           // over BN*CHN*HWSZ/4
    const int q = HWSZ/4;
    int p = idx % q;
    int o = (idx/q) % CHN;
    int b = idx/(q*CHN);
    const float4* x4 = (const float4*)(x + (size_t)b*HWSZ);
    float4 v = x4[p];
    float wv = w0[o], bv = b0[o];
    float4 r;
    r.x = fmaf(wv, v.x, bv); r.y = fmaf(wv, v.y, bv);
    r.z = fmaf(wv, v.z, bv); r.w = fmaf(wv, v.w, bv);
    ((float4*)out)[idx] = r;
}

// PAC conv as implicit GEMM on MFMA: Out[64o x 64px] = W[64 x 576] * V[576 x 64],
// V[(t,c),n] = bf16(h[c, q_t(p0+n)] * K[t, p0+n]).  fp32 accumulate.
// 4 waves: wave w owns o-range [16w,16w+16), all 64 pixels (4 n-subtiles).
// V staged per 32-k step into double-buffered LDS, row stride 40 shorts (80 B)
// -> 2-way bank aliasing only. A pre-packed, L1-hot dwordx4 per step.
template<bool HASK, bool FRELU>
__global__ void __launch_bounds__(256, 4) pac_mfma(
    const float* __restrict__ h, const float* __restrict__ Kb,
    const short* __restrict__ Ap, const float* __restrict__ bias,
    float* __restrict__ out)
{
    __shared__ short8 ldsv[2*64*5];   // 2 bufs x 64 n x 40 shorts = 10240 B

    int b  = blockIdx.z;
    int y  = blockIdx.y;
    int x0 = blockIdx.x * NT;
    int tid  = threadIdx.x;
    int lane = tid & 63;
    int wave = tid >> 6;
    int ln   = lane & 15;
    int quad = lane >> 4;
    int n  = lane;        // staged pixel index for this thread
    int kg = wave;        // staged k-group (8 channels)

    const float* hb = h + (size_t)b*CHN*HWSZ;
    int scol[3];
#pragma unroll
    for (int d = 0; d < 3; ++d) scol[d] = refl(x0 + n + d - 1, WW);

    floatx4 acc[4];
#pragma unroll
    for (int s = 0; s < 4; ++s) acc[s] = (floatx4){0.f, 0.f, 0.f, 0.f};

    const short8* Ap8 = (const short8*)Ap;
    int buf = 0;

#pragma unroll
    for (int t = 0; t < 9; ++t) {
        int srow = refl(y + t/3 - 1, HH);
        float mK = 1.0f;
        if (HASK) mK = Kb[((size_t)(b*9 + t))*HWSZ + y*WW + x0 + n];
        const float* hrow = hb + srow*WW + scol[t%3];
#pragma unroll
        for (int kh = 0; kh < 2; ++kh) {
            // ---- stage V[32 x 64] (this thread: 8 channels, 1 pixel) ----
            const float* hp = hrow + (size_t)(kh*32 + kg*8)*HWSZ;
            float v[8];
#pragma unroll
            for (int j = 0; j < 8; ++j) v[j] = hp[(size_t)j*HWSZ];
            short8 pk;
#pragma unroll
            for (int j = 0; j < 8; ++j) pk[j] = f2bf(v[j]*mK);
            ldsv[buf*320 + n*5 + kg] = pk;
            __syncthreads();
            // ---- MFMA: 1 A-frag load + 4 B-frags + 4 mfma per wave ----
            short8 afr = Ap8[((t*2 + kh)*4 + wave)*64 + lane];
#pragma unroll
            for (int s = 0; s < 4; ++s) {
                short8 bfr = ldsv[buf*320 + (s*16 + ln)*5 + quad];
                acc[s] = __builtin_amdgcn_mfma_f32_16x16x32_bf16(afr, bfr, acc[s], 0, 0, 0);
            }
            buf ^= 1;
        }
    }

    // epilogue: C/D layout col=lane&15 (pixel), row=quad*4+reg (o within stripe)
    float bv[4];
#pragma unroll
    for (int r = 0; r < 4; ++r) bv[r] = bias[wave*16 + quad*4 + r];
    float* ob = out + (size_t)b*CHN*HWSZ;
#pragma unroll
    for (int s = 0; s < 4; ++s) {
#pragma unroll
        for (int r = 0; r < 4; ++r) {
            int o = wave*16 + quad*4 + r;
            int p = y*WW + x0 + s*16 + ln;
            float val = acc[s][r] + bv[r];
            if (FRELU) val = fmaxf(val, 0.f);
            ob[(size_t)o*HWSZ + p] = val;
        }
    }
}

// per-(b,c) mean / rstd over HWSZ
__global__ void __launch_bounds__(256) stats_kernel(const float* __restrict__ xin,
                                                    float* __restrict__ stats) {
    int bc = blockIdx.x;
    const float4* p4 = (const float4*)(xin + (size_t)bc*HWSZ);
    float s1 = 0.f, s2 = 0.f;
    for (int i = threadIdx.x; i < HWSZ/4; i += 256) {
        float4 v = p4[i];
        s1 += v.x + v.y + v.z + v.w;
        s2 += v.x*v.x + v.y*v.y + v.z*v.z + v.w*v.w;
    }
#pragma unroll
    for (int d = 32; d; d >>= 1) { s1 += __shfl_down(s1, d); s2 += __shfl_down(s2, d); }
    __shared__ float ls[8];
    int wid = threadIdx.x >> 6;
    if ((threadIdx.x & 63) == 0) { ls[wid] = s1; ls[wid+4] = s2; }
    __syncthreads();
    if (threadIdx.x == 0) {
        float t1 = ls[0]+ls[1]+ls[2]+ls[3];
        float t2 = ls[4]+ls[5]+ls[6]+ls[7];
        float mean = t1 * (1.f/HWSZ);
        float var  = t2 * (1.f/HWSZ) - mean*mean;
        stats[bc*2]   = mean;
        stats[bc*2+1] = rsqrtf(fmaxf(var, 0.f) + EPSV);
    }
}

__global__ void applyrelu_kernel(float* __restrict__ xio, const float* __restrict__ stats) {
    int idx = blockIdx.x*256 + threadIdx.x;           // BN*CHN*HWSZ/4
    int bc = idx / (HWSZ/4);
    float mean = stats[bc*2], r = stats[bc*2+1];
    float4 v = ((float4*)xio)[idx];
    v.x = fmaxf((v.x-mean)*r, 0.f);
    v.y = fmaxf((v.y-mean)*r, 0.f);
    v.z = fmaxf((v.z-mean)*r, 0.f);
    v.w = fmaxf((v.w-mean)*r, 0.f);
    ((float4*)xio)[idx] = v;
}

// a = relu(a + (c - mean)*rstd)
__global__ void addnorm_relu_kernel(float* __restrict__ a, const float* __restrict__ cc,
                                    const float* __restrict__ stats) {
    int idx = blockIdx.x*256 + threadIdx.x;           // BN*CHN*HWSZ/4
    int bc = idx / (HWSZ/4);
    float mean = stats[bc*2], r = stats[bc*2+1];
    float4 t = ((float4*)a)[idx];
    float4 v = ((const float4*)cc)[idx];
    t.x = fmaxf(t.x + (v.x-mean)*r, 0.f);
    t.y = fmaxf(t.y + (v.y-mean)*r, 0.f);
    t.z = fmaxf(t.z + (v.z-mean)*r, 0.f);
    t.w = fmaxf(t.w + (v.w-mean)*r, 0.f);
    ((float4*)a)[idx] = t;
}

extern "C" void kernel_launch(void* const* d_in, const int* in_sizes, int n_in,
                              void* d_out, int out_size, void* d_ws, size_t ws_size,
                              hipStream_t stream) {
    const float* x   = (const float*)d_in[0];
    // d_in[1] = grad_img: unused by the reference
    const float* w0  = (const float*)d_in[2];
    const float* b0  = (const float*)d_in[3];
    const float* wf  = (const float*)d_in[4];
    const float* bf  = (const float*)d_in[5];
    const float* w1a = (const float*)d_in[6];  const float* b1a = (const float*)d_in[7];
    const float* w1b = (const float*)d_in[8];  const float* b1b = (const float*)d_in[9];
    const float* w2a = (const float*)d_in[10]; const float* b2a = (const float*)d_in[11];
    const float* w2b = (const float*)d_in[12]; const float* b2b = (const float*)d_in[13];
    const float* w3a = (const float*)d_in[14]; const float* b3a = (const float*)d_in[15];
    const float* w3b = (const float*)d_in[16]; const float* b3b = (const float*)d_in[17];

    float* ws    = (float*)d_ws;
    float* Kb    = ws;                               // BN*9*HWSZ      = 2,359,296 f
    float* A     = Kb + (size_t)BN*9*HWSZ;           // BN*CHN*HWSZ    = 4,194,304 f
    float* Bb    = A  + (size_t)BN*CHN*HWSZ;         // BN*CHN*HWSZ
    float* stats = Bb + (size_t)BN*CHN*HWSZ;         // BN*CHN*2
    short* Apk   = (short*)(stats + BN*CHN*2);       // 7 * 36864 bf16 = 516 KB
    float* Cc    = (float*)d_out;                    // scratch + final output

    const int WPACK = 9*2*4*64*8;                    // 36864 elements per layer
    const float* wsrc[7] = {w1a, w1b, w2a, w2b, w3a, w3b, wf};
    for (int i = 0; i < 7; ++i)
        pack_w<<<(WPACK + 255)/256, 256, 0, stream>>>(wsrc[i], Apk + (size_t)i*WPACK);

    guide_kernel<<<(BN*HWSZ + 255)/256, 256, 0, stream>>>(x, Kb);
    conv1x1_kernel<<<BN*CHN*HWSZ/4/256, 256, 0, stream>>>(x, w0, b0, A);

    dim3 g(WW/NT, HH, BN);                           // 4 x 256 x 4 = 4096 blocks
    const int eblk = BN*CHN*HWSZ/4/256;
    const float* biasA[3] = {b1a, b2a, b3a};
    const float* biasB[3] = {b1b, b2b, b3b};

    for (int rb = 0; rb < 3; ++rb) {
        pac_mfma<true,false><<<g, 256, 0, stream>>>(A, Kb, Apk + (size_t)(2*rb)*WPACK, biasA[rb], Bb);
        stats_kernel<<<BN*CHN, 256, 0, stream>>>(Bb, stats);
        applyrelu_kernel<<<eblk, 256, 0, stream>>>(Bb, stats);
        pac_mfma<true,false><<<g, 256, 0, stream>>>(Bb, Kb, Apk + (size_t)(2*rb+1)*WPACK, biasB[rb], Cc);
        stats_kernel<<<BN*CHN, 256, 0, stream>>>(Cc, stats);
        addnorm_relu_kernel<<<eblk, 256, 0, stream>>>(A, Cc, stats);
    }

    // final: plain 3x3 conv (no K modulation) + bias + relu
    pac_mfma<false,true><<<g, 256, 0, stream>>>(A, Kb, Apk + (size_t)6*WPACK, bf, Cc);
}

// Round 4
// 545.437 us; speedup vs baseline: 13.0379x; 1.8581x over previous
//
#include <hip/hip_runtime.h>
#include <hip/hip_bf16.h>
#include <math.h>

#define BN 4
#define CHN 64
#define HH 256
#define WW 256
#define HWSZ (HH*WW)
#define EPSV 1e-5f
#define CP 72   // LDS channel-dim pad in shorts: 144B row stride -> 16B-aligned b128, balanced banks

typedef __attribute__((ext_vector_type(8)))  short  short8;
typedef __attribute__((ext_vector_type(4)))  short  short4v;
typedef __attribute__((ext_vector_type(16))) float  floatx16;

__device__ __forceinline__ int refl(int i, int n){ if(i<0)i=-i; if(i>=n)i=2*n-2-i; return i; }
__device__ __forceinline__ short f2bf(float f){ __hip_bfloat16 h=__float2bfloat16(f); return __builtin_bit_cast(short,h); }
__device__ __forceinline__ float bf2f(short s){ unsigned u=((unsigned)(unsigned short)s)<<16; return __builtin_bit_cast(float,u); }

// ---------------- guide: K[b,t,y,x] = exp(-0.5*(g_shift - g)^2), fp32 ----------------
__global__ void guide_kernel(const float* __restrict__ x, float* __restrict__ Kb) {
    int idx = blockIdx.x * 256 + threadIdx.x;
    if (idx >= BN*HWSZ) return;
    int b = idx / HWSZ, p = idx - b*HWSZ;
    int y = p / WW, xx = p - y*WW;
    const float* g = x + b*HWSZ;
    float gc = g[p];
#pragma unroll
    for (int t = 0; t < 9; ++t) {
        int yy  = refl(y + t/3 - 1, HH);
        int xx2 = refl(xx + t%3 - 1, WW);
        float d = g[yy*WW + xx2] - gc;
        Kb[(b*9 + t)*HWSZ + p] = __expf(-0.5f*d*d);
    }
}

// ---------------- pack all 7 weight tensors into 32x32x16 A-fragment order ----------------
// frag = (t*4+cg)*2+oh ; o = oh*32+(lane&31) ; c = cg*16+(lane>>5)*8+j
__global__ void pack_all(const float* w1,const float* w2,const float* w3,const float* w4,
                         const float* w5,const float* w6,const float* w7, short* __restrict__ Ap){
    const float* wsrc[7] = {w1,w2,w3,w4,w5,w6,w7};
    int layer = blockIdx.y;
    int tid = blockIdx.x*256 + threadIdx.x;          // 0..36863
    int j    = tid & 7;
    int lane = (tid >> 3) & 63;
    int frag = tid >> 9;                             // 0..71
    int oh = frag & 1, cg = (frag >> 1) & 3, t = frag >> 3;
    int o = oh*32 + (lane & 31);
    int c = cg*16 + (lane >> 5)*8 + j;
    Ap[(size_t)layer*36864 + tid] = f2bf(wsrc[layer][(o*CHN + c)*9 + t]);
}

// ---------------- conv1x1 -> A, channels-last bf16 [b][y][x][c] ----------------
__global__ void conv1x1_kernel(const float* __restrict__ x, const float* __restrict__ w0,
                               const float* __restrict__ b0, short* __restrict__ A){
    int idx = blockIdx.x*256 + threadIdx.x;          // BN*HWSZ*8 (px-octets)
    int oc = idx & 7;
    int px = (idx >> 3) % HWSZ;
    int b  = idx / (HWSZ*8);
    float xv = x[(size_t)b*HWSZ + px];
    short8 r;
#pragma unroll
    for (int j = 0; j < 8; ++j) {
        int c = oc*8 + j;
        r[j] = f2bf(fmaf(w0[c], xv, b0[c]));
    }
    *(short8*)(A + ((size_t)(b*HWSZ + px))*64 + oc*8) = r;
}

// ---------------- zero the stats accumulators (6 layers x [4][64][2]) ----------------
__global__ void zero_stats(float* st){
    int idx = blockIdx.x*256 + threadIdx.x;
    if (idx < 6*BN*64*2) st[idx] = 0.f;
}

// ---------------- PAC conv, implicit GEMM on mfma_32x32x16_bf16 ----------------
// Block: 64 o x (32 px x 2 rows). Wave(oh=w&1, wrow=w>>1): 32 o x 32 px.
// h halo (4 rows x 34 px x 64 c, bf16 channels-last) staged to LDS ONCE; taps read
// shifted windows. K applied per tap on the C-tile (col=lane&31 = pixel):
//   acc += K[t,px] * (W_t x h_shift)  -- B-frags are RAW h, no per-element modulate.
// NORM=1: staging applies (v-mean)*rstd,relu from sum/sumsq stats (fuses applyrelu).
template<int NORM, int HASK, int FINAL>
__global__ void __launch_bounds__(256, 4) pac_mfma(
    const short* __restrict__ hin, const float* __restrict__ Kb,
    const short* __restrict__ Ap, const float* __restrict__ bias,
    const float* __restrict__ stin, short* __restrict__ outb, float* __restrict__ outf)
{
    __shared__ short lds[4*34*CP];                   // 19584 B

    int b  = blockIdx.z;
    int y0 = blockIdx.y * 2;
    int x0 = blockIdx.x * 32;
    int tid = threadIdx.x, lane = tid & 63, wave = tid >> 6;
    int ln2 = lane & 31, hi = lane >> 5, oh = wave & 1, wrow = wave >> 1;
    const short* hb = hin + (size_t)b*HWSZ*64;
    const float* stb = stin + b*64*2;

    // ---- bulk stage: 4 rows x 32 px x 64 c, 16B chunks, fully coalesced ----
    float mean[8], rstd[8];
    if (NORM) {
        int c0 = (tid & 7) * 8;                      // thread's c-octet is fixed (256%8==0)
#pragma unroll
        for (int j = 0; j < 8; ++j) {
            float s = stb[(c0+j)*2], s2 = stb[(c0+j)*2+1];
            float m = s * (1.f/HWSZ);
            float var = s2 * (1.f/HWSZ) - m*m;
            mean[j] = m; rstd[j] = rsqrtf(fmaxf(var, 0.f) + EPSV);
        }
    }
#pragma unroll
    for (int it = 0; it < 4; ++it) {
        int chunk = tid + it*256;                    // 1024 chunks
        int r = chunk >> 8, o = chunk & 255, px = o >> 3, oc = o & 7;
        int yy = refl(y0 - 1 + r, HH);
        short8 v = *(const short8*)(hb + ((size_t)(yy*WW + x0 + px))*64 + oc*8);
        if (NORM) {
#pragma unroll
            for (int j = 0; j < 8; ++j) {
                float f = bf2f(v[j]);
                f = fmaxf((f - mean[j]) * rstd[j], 0.f);
                v[j] = f2bf(f);
            }
        }
        *(short8*)(lds + (r*34 + 1 + px)*CP + oc*8) = v;
    }
    // ---- halo columns x0-1 and x0+32 (x-reflected at edges) ----
    {
        int r = tid >> 6, c = tid & 63;
        int xm = (x0 == 0) ? 1 : x0 - 1;
        int xp = (x0 + 32 == WW) ? WW - 2 : x0 + 32;
        int yy = refl(y0 - 1 + r, HH);
        float fa = bf2f(hb[((size_t)(yy*WW + xm))*64 + c]);
        float fb = bf2f(hb[((size_t)(yy*WW + xp))*64 + c]);
        if (NORM) {
            float s = stb[c*2], s2 = stb[c*2+1];
            float m = s * (1.f/HWSZ);
            float rs = rsqrtf(fmaxf(s2*(1.f/HWSZ) - m*m, 0.f) + EPSV);
            fa = fmaxf((fa - m)*rs, 0.f);
            fb = fmaxf((fb - m)*rs, 0.f);
        }
        lds[(r*34 + 0)*CP + c]  = f2bf(fa);
        lds[(r*34 + 33)*CP + c] = f2bf(fb);
    }
    __syncthreads();

    // ---- per-lane K values (pixel = x0+ln2, row = y0+wrow) ----
    float kv[9];
    if (HASK) {
#pragma unroll
        for (int t = 0; t < 9; ++t)
            kv[t] = Kb[((size_t)(b*9 + t))*HWSZ + (y0 + wrow)*WW + x0 + ln2];
    }

    floatx16 acc = (floatx16)(0.f);
    const short8* Ap8 = (const short8*)Ap;
#pragma unroll
    for (int t = 0; t < 9; ++t) {
        int dy = t/3 - 1, dx = t%3 - 1;
        int rr = wrow + dy + 1;                      // 0..3
        floatx16 tmp;
#pragma unroll
        for (int cg = 0; cg < 4; ++cg) {
            short8 bf = *(const short8*)(lds + (rr*34 + 1 + ln2 + dx)*CP + cg*16 + hi*8);
            short8 af = Ap8[((size_t)(t*4 + cg)*2 + oh)*64 + lane];
            if (HASK)
                tmp = __builtin_amdgcn_mfma_f32_32x32x16_bf16(af, bf, cg == 0 ? (floatx16)(0.f) : tmp, 0, 0, 0);
            else
                acc = __builtin_amdgcn_mfma_f32_32x32x16_bf16(af, bf, acc, 0, 0, 0);
        }
        if (HASK) {
#pragma unroll
            for (int r = 0; r < 16; ++r) acc[r] = fmaf(kv[t], tmp[r], acc[r]);
        }
    }

    // ---- epilogue: C/D col=lane&31 (px), row o = (reg&3)+8*(reg>>2)+4*hi+32*oh ----
    int y = y0 + wrow, x = x0 + ln2;
#pragma unroll
    for (int q = 0; q < 4; ++q) {
        int o0 = oh*32 + hi*4 + 8*q;                 // regs 4q..4q+3 -> o0..o0+3
        float4 bq = *(const float4*)(bias + o0);
        if (FINAL) {
#pragma unroll
            for (int jj = 0; jj < 4; ++jj) {
                float val = acc[q*4 + jj] + ((float*)&bq)[jj];
                val = fmaxf(val, 0.f);
                outf[((size_t)(b*64 + o0 + jj))*HWSZ + y*WW + x] = val;  // NCHW fp32
            }
        } else {
            short4v pk;
#pragma unroll
            for (int jj = 0; jj < 4; ++jj) pk[jj] = f2bf(acc[q*4 + jj] + ((float*)&bq)[jj]);
            *(short4v*)(outb + ((size_t)b*HWSZ + (size_t)(y*WW + x))*64 + o0) = pk;
        }
    }
}

// ---------------- stats: per-(b,c) sum/sumsq of bf16 channels-last tensor ----------------
__global__ void __launch_bounds__(256) stats_k(const short* __restrict__ t, float* __restrict__ st){
    int b = blockIdx.y, chunk = blockIdx.x;          // 32 chunks of 2048 px
    int tid = threadIdx.x, oc = tid & 7, pxl = tid >> 3;
    const short* tb = t + (size_t)b*HWSZ*64;
    float s[8] = {0}, s2[8] = {0};
    for (int i = 0; i < 64; ++i) {
        int px = chunk*2048 + i*32 + pxl;
        short8 v = *(const short8*)(tb + (size_t)px*64 + oc*8);
#pragma unroll
        for (int j = 0; j < 8; ++j) { float f = bf2f(v[j]); s[j] += f; s2[j] += f*f; }
    }
#pragma unroll
    for (int mask = 8; mask <= 32; mask <<= 1) {
#pragma unroll
        for (int j = 0; j < 8; ++j) { s[j] += __shfl_xor(s[j], mask); s2[j] += __shfl_xor(s2[j], mask); }
    }
    __shared__ float sm[4][8][16];
    int lane = tid & 63, wave = tid >> 6;
    if (lane < 8) {
#pragma unroll
        for (int j = 0; j < 8; ++j) { sm[wave][lane][j] = s[j]; sm[wave][lane][8+j] = s2[j]; }
    }
    __syncthreads();
    if (tid < 8) {
#pragma unroll
        for (int j = 0; j < 8; ++j) {
            float a = 0, bsq = 0;
#pragma unroll
            for (int w = 0; w < 4; ++w) { a += sm[w][tid][j]; bsq += sm[w][tid][8+j]; }
            atomicAdd(&st[(b*64 + tid*8 + j)*2],     a);
            atomicAdd(&st[(b*64 + tid*8 + j)*2 + 1], bsq);
        }
    }
}

// ---------------- A <- relu(A + (C-mean)*rstd), bf16 channels-last ----------------
__global__ void addnorm_relu(short* __restrict__ A, const short* __restrict__ C,
                             const float* __restrict__ st){
    int idx = blockIdx.x*256 + threadIdx.x;          // BN*HWSZ*8
    int oc = idx & 7;
    size_t pq = (size_t)(idx >> 3);
    int b = (int)(pq / HWSZ);
    size_t base = pq*64 + oc*8;
    short8 a = *(short8*)(A + base);
    short8 c = *(const short8*)(C + base);
#pragma unroll
    for (int j = 0; j < 8; ++j) {
        int cc = oc*8 + j;
        float s = st[(b*64+cc)*2], s2 = st[(b*64+cc)*2+1];
        float m = s * (1.f/HWSZ);
        float rs = rsqrtf(fmaxf(s2*(1.f/HWSZ) - m*m, 0.f) + EPSV);
        float f = bf2f(a[j]) + (bf2f(c[j]) - m)*rs;
        a[j] = f2bf(fmaxf(f, 0.f));
    }
    *(short8*)(A + base) = a;
}

extern "C" void kernel_launch(void* const* d_in, const int* in_sizes, int n_in,
                              void* d_out, int out_size, void* d_ws, size_t ws_size,
                              hipStream_t stream) {
    const float* x   = (const float*)d_in[0];
    // d_in[1] = grad_img: unused by the reference
    const float* w0  = (const float*)d_in[2];
    const float* b0  = (const float*)d_in[3];
    const float* wf  = (const float*)d_in[4];
    const float* bf  = (const float*)d_in[5];
    const float* w1a = (const float*)d_in[6];  const float* b1a = (const float*)d_in[7];
    const float* w1b = (const float*)d_in[8];  const float* b1b = (const float*)d_in[9];
    const float* w2a = (const float*)d_in[10]; const float* b2a = (const float*)d_in[11];
    const float* w2b = (const float*)d_in[12]; const float* b2b = (const float*)d_in[13];
    const float* w3a = (const float*)d_in[14]; const float* b3a = (const float*)d_in[15];
    const float* w3b = (const float*)d_in[16]; const float* b3b = (const float*)d_in[17];

    float* ws   = (float*)d_ws;
    float* Kb   = ws;                                 // 2,359,296 f (9.4 MB)
    short* A    = (short*)(Kb + (size_t)BN*9*HWSZ);   // 16,777,216 shorts (33.5 MB)
    short* Bb   = A + (size_t)BN*HWSZ*64;             // 16,777,216 shorts
    short* Apk  = Bb + (size_t)BN*HWSZ*64;            // 7*36864 shorts
    float* st   = (float*)(Apk + (size_t)7*36864 + 64); // 6 * 512 floats
    short* Cc   = (short*)d_out;                      // C scratch (bf16), then fp32 output

    zero_stats<<<12, 256, 0, stream>>>(st);
    pack_all<<<dim3(144, 7), 256, 0, stream>>>(w1a, w1b, w2a, w2b, w3a, w3b, wf, Apk);
    guide_kernel<<<(BN*HWSZ + 255)/256, 256, 0, stream>>>(x, Kb);
    conv1x1_kernel<<<BN*HWSZ*8/256, 256, 0, stream>>>(x, w0, b0, A);

    dim3 g(WW/32, HH/2, BN);                          // 8 x 128 x 4 = 4096 blocks
    const int eblk = BN*HWSZ*8/256;
    const float* biasA[3] = {b1a, b2a, b3a};
    const float* biasB[3] = {b1b, b2b, b3b};

    for (int rb = 0; rb < 3; ++rb) {
        float* stB = st + (size_t)(2*rb)   * BN*64*2;
        float* stC = st + (size_t)(2*rb+1) * BN*64*2;
        // pac_a: raw staging, K-modulated, bf16 out
        pac_mfma<0,1,0><<<g, 256, 0, stream>>>(A, Kb, Apk + (size_t)(2*rb)*36864, biasA[rb],
                                               nullptr, Bb, nullptr);
        stats_k<<<dim3(32, BN), 256, 0, stream>>>(Bb, stB);
        // pac_b: staging applies norm(B)+relu, K-modulated, bf16 out
        pac_mfma<1,1,0><<<g, 256, 0, stream>>>(Bb, Kb, Apk + (size_t)(2*rb+1)*36864, biasB[rb],
                                               stB, Cc, nullptr);
        stats_k<<<dim3(32, BN), 256, 0, stream>>>(Cc, stC);
        addnorm_relu<<<eblk, 256, 0, stream>>>(A, Cc, stC);
    }

    // final: plain 3x3 conv (no K), bias+relu, fp32 NCHW to d_out
    pac_mfma<0,0,1><<<g, 256, 0, stream>>>(A, Kb, Apk + (size_t)6*36864, bf,
                                           nullptr, nullptr, (float*)d_out);
}